// Round 6
// baseline (269.108 us; speedup 1.0000x reference)
//
#include <hip/hip_runtime.h>
#include <stdint.h>
#include <stddef.h>

// MultiHeadAttention: B=2, L=2048, E=1024, H=16, Dh=64. Global dtype f32.
// Internals bf16 MFMA. Pipeline:
//   cvt    : f32 -> bf16 copies of Wq,Wk,Wv,Wo ONLY (x staged as f32 in proj)
//   proj   : A staged f32->LDS, packed to bf16 at frag read. Q (prescaled by
//            0.125*log2e), K -> [B,H,L,Dh]; V -> [B,H,Dh,L]
//   flash  : causal, no-max softmax; K frags DIRECT FROM GLOBAL (no K LDS),
//            V staged+swizzled; paired q-tiles share one kv sweep
//   oproj  : attn @ Wo^T + bo -> d_out f32
// R6: kill cvt's x pass (72MB HBM); halve flash LDS-read pipe.

#define AS1 __attribute__((address_space(1)))
#define AS3 __attribute__((address_space(3)))

typedef __attribute__((ext_vector_type(8))) __bf16 bf16x8;
typedef __attribute__((ext_vector_type(8))) unsigned short u16x8;
typedef __attribute__((ext_vector_type(4))) unsigned short u16x4;
typedef __attribute__((ext_vector_type(4))) float f32x4;
typedef __attribute__((ext_vector_type(2))) unsigned int u32x2;
typedef __attribute__((ext_vector_type(4))) unsigned int u32x4;

// 0.125 * log2(e): folds 1/sqrt(Dh) AND exp->exp2 conversion into Q
#define QSCALE 0.18033688011112042f

static __device__ __forceinline__ unsigned short f2bf(float f) {
  unsigned int u = __builtin_bit_cast(unsigned int, f);
  u += 0x7fffu + ((u >> 16) & 1u);   // RNE
  return (unsigned short)(u >> 16);
}
// pack two f32 -> bf16 pair by truncation (1 v_perm)
static __device__ __forceinline__ unsigned int pkbf(float lo, float hi) {
  return __builtin_amdgcn_perm(__builtin_bit_cast(unsigned int, hi),
                               __builtin_bit_cast(unsigned int, lo), 0x07060302u);
}
static __device__ __forceinline__ void g2l16(const unsigned short* g, unsigned short* l) {
  __builtin_amdgcn_global_load_lds((AS1 void*)g, (AS3 void*)l, 16, 0, 0);
}
static __device__ __forceinline__ void g2l16f(const float* g, float* l) {
  __builtin_amdgcn_global_load_lds((AS1 void*)g, (AS3 void*)l, 16, 0, 0);
}
static __device__ __forceinline__ float fexp2(float x) {
  return __builtin_amdgcn_exp2f(x);
}

// ---------------------------------------------------------------------------
// f32 -> bf16 convert, weights only (4 x 1M elems)
// ---------------------------------------------------------------------------
__global__ __launch_bounds__(256) void cvt_kernel(
    const float* __restrict__ s0, const float* __restrict__ s1,
    const float* __restrict__ s2, const float* __restrict__ s3,
    unsigned short* __restrict__ d0, unsigned short* __restrict__ d1,
    unsigned short* __restrict__ d2, unsigned short* __restrict__ d3)
{
  const int z = blockIdx.z;
  const float* s = (z == 0) ? s0 : (z == 1) ? s1 : (z == 2) ? s2 : s3;
  unsigned short* d = (z == 0) ? d0 : (z == 1) ? d1 : (z == 2) ? d2 : d3;
  int i = (blockIdx.x * 256 + threadIdx.x) * 8;
  f32x4 a = *(const f32x4*)(s + i);
  f32x4 b = *(const f32x4*)(s + i + 4);
  u16x8 r;
  r[0] = f2bf(a[0]); r[1] = f2bf(a[1]); r[2] = f2bf(a[2]); r[3] = f2bf(a[3]);
  r[4] = f2bf(b[0]); r[5] = f2bf(b[1]); r[6] = f2bf(b[2]); r[7] = f2bf(b[3]);
  *(u16x8*)(d + i) = r;
}

// ---------------------------------------------------------------------------
// GEMM: out[m,n] = (sum_k A[m,k]*Bw[n,k] + bias[n]) * oscale
// BM x 128 tile, BK=32, double-buffered LDS, ONE barrier per K-iter.
// AF32: A staged as f32 (8 x 16B chunks/row, slot sl holds chunk sl^(row&7)),
//       packed to bf16 at fragment read. Else A bf16 (4 chunks, sl^((row>>1)&3)).
// B always bf16. All reads 2-way-per-phase conflict-free.
// ---------------------------------------------------------------------------
template<int BM, bool AF32>
static __device__ __forceinline__ void gemm_bt(
    const void* __restrict__ Av,
    const unsigned short* __restrict__ Bw,
    const float* __restrict__ bias,
    unsigned short* __restrict__ outb,
    float* __restrict__ outf,
    int K, int N, int mode, float oscale)
{
  constexpr int MT = BM / 32;
  constexpr int WROWS = BM / 2;
  __shared__ __align__(16) float          Asf[AF32 ? 2 : 1][AF32 ? BM * 32 : 1];
  __shared__ __align__(16) unsigned short Asb[AF32 ? 1 : 2][AF32 ? 1 : BM * 32];
  __shared__ __align__(16) unsigned short Bs[2][128 * 32];

  const int t    = threadIdx.x;
  const int lane = t & 63;
  const int w    = t >> 6;
  const int quad = lane >> 4;
  const int l15  = lane & 15;
  const int wm   = (w >> 1) * WROWS;
  const int wn   = (w & 1) * 64;
  const int m0   = blockIdx.x * BM;
  const int n0   = blockIdx.y * 128;

  const float* Af          = (const float*)Av;
  const unsigned short* Ab = (const unsigned short*)Av;

  f32x4 acc[MT][4];
  const f32x4 zero = {0.f, 0.f, 0.f, 0.f};
#pragma unroll
  for (int mt = 0; mt < MT; ++mt)
#pragma unroll
    for (int nt = 0; nt < 4; ++nt) acc[mt][nt] = zero;

  auto stage = [&](int buf, int k0) {
    if (AF32) {
#pragma unroll
      for (int i = 0; i < BM / 32; ++i) {     // BM*8 chunks of 16B (4 f32)
        int c = t + i * 256;
        int row = c >> 3, sl = c & 7;
        int g = sl ^ (row & 7);
        g2l16f(Af + (size_t)(m0 + row) * K + (k0 + g * 4), &Asf[buf][c * 4]);
      }
    } else {
#pragma unroll
      for (int i = 0; i < BM / 64; ++i) {     // BM*4 chunks of 16B (8 bf16)
        int c = t + i * 256;
        int row = c >> 2, sl = c & 3;
        int g = sl ^ ((row >> 1) & 3);
        g2l16(Ab + (size_t)(m0 + row) * K + (k0 + g * 8), &Asb[buf][c * 8]);
      }
    }
#pragma unroll
    for (int i = 0; i < 2; ++i) {
      int c = t + i * 256;
      int row = c >> 2, sl = c & 3;
      int g = sl ^ ((row >> 1) & 3);
      g2l16(Bw + (size_t)(n0 + row) * K + (k0 + g * 8), &Bs[buf][c * 8]);
    }
  };

  stage(0, 0);
  const int nk = K >> 5;
  for (int kt = 0; kt < nk; ++kt) {
    __syncthreads();
    if (kt + 1 < nk) stage((kt + 1) & 1, (kt + 1) * 32);
    const int b = kt & 1;

    bf16x8 af[MT], bfr[4];
#pragma unroll
    for (int mt = 0; mt < MT; ++mt) {
      int r = wm + mt * 16 + l15;
      if (AF32) {
        int h = r & 7;
        const float* Ar = &Asf[b][r * 32];
        f32x4 a0 = *(const f32x4*)(Ar + (((2 * quad)     ^ h) * 4));
        f32x4 a1 = *(const f32x4*)(Ar + (((2 * quad + 1) ^ h) * 4));
        u32x4 pr;
        pr[0] = pkbf(a0[0], a0[1]); pr[1] = pkbf(a0[2], a0[3]);
        pr[2] = pkbf(a1[0], a1[1]); pr[3] = pkbf(a1[2], a1[3]);
        af[mt] = __builtin_bit_cast(bf16x8, pr);
      } else {
        af[mt] = *(const bf16x8*)(&Asb[b][r * 32 + ((quad ^ ((r >> 1) & 3)) * 8)]);
      }
    }
#pragma unroll
    for (int nt = 0; nt < 4; ++nt) {
      int r = wn + nt * 16 + l15;
      bfr[nt] = *(const bf16x8*)(&Bs[b][r * 32 + ((quad ^ ((r >> 1) & 3)) * 8)]);
    }
#pragma unroll
    for (int mt = 0; mt < MT; ++mt)
#pragma unroll
      for (int nt = 0; nt < 4; ++nt)
        acc[mt][nt] = __builtin_amdgcn_mfma_f32_16x16x32_bf16(af[mt], bfr[nt], acc[mt][nt], 0, 0, 0);
  }

#pragma unroll
  for (int nt = 0; nt < 4; ++nt) {
    int n = n0 + wn + nt * 16 + l15;
    float bv = bias[n];
#pragma unroll
    for (int mt = 0; mt < MT; ++mt) {
#pragma unroll
      for (int r = 0; r < 4; ++r) {
        int m = m0 + wm + mt * 16 + quad * 4 + r;
        float val = (acc[mt][nt][r] + bv) * oscale;
        if (mode == 0) {
          outf[(size_t)m * N + n] = val;
        } else {
          int b2 = m >> 11, l = m & 2047, h = n >> 6, d = n & 63;
          size_t idx;
          if (mode == 1) idx = ((size_t)(b2 * 16 + h) * 2048 + l) * 64 + d;
          else           idx = ((size_t)(b2 * 16 + h) * 64 + d) * 2048 + l;
          outb[idx] = f2bf(val);
        }
      }
    }
  }
}

__global__ __launch_bounds__(256, 3) void proj_kernel(
    const float* __restrict__ xq, const float* __restrict__ xk,
    const float* __restrict__ xv,
    const unsigned short* __restrict__ Wq, const float* __restrict__ bq,
    const unsigned short* __restrict__ Wk, const float* __restrict__ bk,
    const unsigned short* __restrict__ Wv, const float* __restrict__ bv,
    unsigned short* __restrict__ Qws, unsigned short* __restrict__ Kws,
    unsigned short* __restrict__ Vtws)
{
  int z = blockIdx.z;
  const float* A          = (z == 0) ? xq : (z == 1) ? xk : xv;
  const unsigned short* W = (z == 0) ? Wq : (z == 1) ? Wk : Wv;
  const float* bias       = (z == 0) ? bq : (z == 1) ? bk : bv;
  unsigned short* out     = (z == 0) ? Qws : (z == 1) ? Kws : Vtws;
  float oscale            = (z == 0) ? QSCALE : 1.0f;
  gemm_bt<128, true>(A, W, bias, out, nullptr, 1024, 1024, (z == 2) ? 2 : 1, oscale);
}

__global__ __launch_bounds__(256, 4) void oproj_kernel(
    const unsigned short* __restrict__ Ain, const unsigned short* __restrict__ Wo,
    const float* __restrict__ bo, float* __restrict__ out)
{
  gemm_bt<64, false>(Ain, Wo, bo, nullptr, out, 1024, 1024, 0, 1.0f);
}

// ---------------------------------------------------------------------------
// Causal flash attention, transposed, no-max softmax, fused paired q-tiles.
// Q,K: [B*H, 2048, 64] bf16 (Q prescaled by QSCALE); Vt: [B*H, 64, 2048].
// K fragments loaded DIRECTLY from global (no K LDS, no reuse to exploit);
// V staged+swizzled in LDS (shared by 4 waves). 1 barrier/iter (V dbuf).
// ---------------------------------------------------------------------------
__global__ __launch_bounds__(256, 3) void flash_kernel(
    const unsigned short* __restrict__ Q,
    const unsigned short* __restrict__ Km,
    const unsigned short* __restrict__ Vt,
    unsigned short* __restrict__ Ao)
{
  __shared__ __align__(16) unsigned short Vs[2][64 * 64];
  __shared__ __align__(16) unsigned short PsA[4][16 * 64];
  __shared__ __align__(16) unsigned short PsB[4][16 * 64];

  const int t    = threadIdx.x;
  const int lane = t & 63;
  const int w    = t >> 6;
  const int quad = lane >> 4;
  const int l15  = lane & 15;
  const int pi   = blockIdx.x;      // 0..15
  const int bh   = blockIdx.y;
  const int qtA  = 31 - pi;
  const int qtB  = pi;              // qtB < qtA always

  const unsigned short* Qb = Q  + (size_t)bh * 2048 * 64;
  const unsigned short* Kb = Km + (size_t)bh * 2048 * 64;
  const unsigned short* Vb = Vt + (size_t)bh * 64 * 2048;
  const int bb = bh >> 4, hh = bh & 15;

  const f32x4 zero = {0.f, 0.f, 0.f, 0.f};

  // Q fragments, B-operand layout (n=q=l15, k=d=quad*8+j), 2 k-steps
  bf16x8 qfA[2], qfB[2];
#pragma unroll
  for (int s = 0; s < 2; ++s) {
    qfA[s] = *(const bf16x8*)(Qb + (size_t)(qtA * 64 + w * 16 + l15) * 64 + s * 32 + quad * 8);
    qfB[s] = *(const bf16x8*)(Qb + (size_t)(qtB * 64 + w * 16 + l15) * 64 + s * 32 + quad * 8);
  }

  f32x4 oA[4], oB[4];
#pragma unroll
  for (int mt = 0; mt < 4; ++mt) { oA[mt] = zero; oB[mt] = zero; }
  float lA = 0.f, lB = 0.f;

  auto stage = [&](int buf, int kv0) {
#pragma unroll
    for (int i = 0; i < 2; ++i) {
      int c = t + i * 256;
      int row = c >> 3, sl = c & 7;
      int g = sl ^ (row & 7);
      g2l16(Vb + (size_t)row * 2048 + kv0 + g * 8, &Vs[buf][c * 8]);
    }
  };

  stage(0, 0);

  // P-store address (wave-private): row q=l15; b64 chunk c=mt*4+quad at
  // elem off ((mt*2+(quad>>1))^(l15&7))*8 + (quad&1)*4  (bank-optimal)
  const int pwr = l15 * 64 + (quad & 1) * 4;
  const int pu0 = quad >> 1;
  const int ph  = l15 & 7;

#pragma unroll 1
  for (int it = 0; it <= qtA; ++it) {
    const int kv0 = it * 64;
    __syncthreads();
    const int cur = it & 1;
    if (it < qtA) stage(cur ^ 1, kv0 + 64);
    const bool doB = (it <= qtB);

    // K fragments straight from global, A-operand layout (m=kv=mt*16+l15, k=d)
    bf16x8 kf[4][2];
#pragma unroll
    for (int mt = 0; mt < 4; ++mt) {
      const unsigned short* Kr = Kb + (size_t)(kv0 + mt * 16 + l15) * 64 + quad * 8;
#pragma unroll
      for (int s = 0; s < 2; ++s)
        kf[mt][s] = *(const bf16x8*)(Kr + s * 32);
    }

    // S^T = K Q^T : D[row=kv_local=mt*16+quad*4+r][col=q=l15]
    f32x4 sA[4], sB[4];
#pragma unroll
    for (int mt = 0; mt < 4; ++mt) {
      f32x4 z = zero;
      z = __builtin_amdgcn_mfma_f32_16x16x32_bf16(kf[mt][0], qfA[0], z, 0, 0, 0);
      z = __builtin_amdgcn_mfma_f32_16x16x32_bf16(kf[mt][1], qfA[1], z, 0, 0, 0);
      sA[mt] = z;
    }
    if (doB) {
#pragma unroll
      for (int mt = 0; mt < 4; ++mt) {
        f32x4 z = zero;
        z = __builtin_amdgcn_mfma_f32_16x16x32_bf16(kf[mt][0], qfB[0], z, 0, 0, 0);
        z = __builtin_amdgcn_mfma_f32_16x16x32_bf16(kf[mt][1], qfB[1], z, 0, 0, 0);
        sB[mt] = z;
      }
    }

    // causal mask on diagonal tiles: kv_local > q_local
    const int qloc = w * 16 + l15;
    if (it == qtA) {
#pragma unroll
      for (int mt = 0; mt < 4; ++mt)
#pragma unroll
        for (int r = 0; r < 4; ++r)
          if (mt * 16 + quad * 4 + r > qloc) sA[mt][r] = -30000.f;
    }
    if (it == qtB) {
#pragma unroll
      for (int mt = 0; mt < 4; ++mt)
#pragma unroll
        for (int r = 0; r < 4; ++r)
          if (mt * 16 + quad * 4 + r > qloc) sB[mt][r] = -30000.f;
    }

    // exp2 (no max subtraction — scores bounded), per-lane partial row-sum,
    // pack 4 bf16 -> one ds_write_b64 per mt
#pragma unroll
    for (int mt = 0; mt < 4; ++mt) {
      float p0 = fexp2(sA[mt][0]), p1 = fexp2(sA[mt][1]);
      float p2 = fexp2(sA[mt][2]), p3 = fexp2(sA[mt][3]);
      lA += (p0 + p1) + (p2 + p3);
      u32x2 pk = {pkbf(p0, p1), pkbf(p2, p3)};
      *(u32x2*)(&PsA[w][pwr + (((mt * 2 + pu0) ^ ph) * 8)]) = pk;
    }
    if (doB) {
#pragma unroll
      for (int mt = 0; mt < 4; ++mt) {
        float p0 = fexp2(sB[mt][0]), p1 = fexp2(sB[mt][1]);
        float p2 = fexp2(sB[mt][2]), p3 = fexp2(sB[mt][3]);
        lB += (p0 + p1) + (p2 + p3);
        u32x2 pk = {pkbf(p0, p1), pkbf(p2, p3)};
        *(u32x2*)(&PsB[w][pwr + (((mt * 2 + pu0) ^ ph) * 8)]) = pk;
      }
    }

    // O^T += Vt P^T : A = Vs (m=d=mt*16+l15, k=kv), B = P (n=q=l15, k=kv)
    bf16x8 pfA[2], pfB[2];
#pragma unroll
    for (int s = 0; s < 2; ++s)
      pfA[s] = *(const bf16x8*)(&PsA[w][l15 * 64 + (((s * 4 + quad) ^ ph) * 8)]);
    if (doB) {
#pragma unroll
      for (int s = 0; s < 2; ++s)
        pfB[s] = *(const bf16x8*)(&PsB[w][l15 * 64 + (((s * 4 + quad) ^ ph) * 8)]);
    }
#pragma unroll
    for (int mt = 0; mt < 4; ++mt) {
      int dd = mt * 16 + l15;
      bf16x8 vf0 = *(const bf16x8*)(&Vs[cur][dd * 64 + (((quad)     ^ (dd & 7)) * 8)]);
      bf16x8 vf1 = *(const bf16x8*)(&Vs[cur][dd * 64 + (((4 + quad) ^ (dd & 7)) * 8)]);
      oA[mt] = __builtin_amdgcn_mfma_f32_16x16x32_bf16(vf0, pfA[0], oA[mt], 0, 0, 0);
      oA[mt] = __builtin_amdgcn_mfma_f32_16x16x32_bf16(vf1, pfA[1], oA[mt], 0, 0, 0);
      if (doB) {
        oB[mt] = __builtin_amdgcn_mfma_f32_16x16x32_bf16(vf0, pfB[0], oB[mt], 0, 0, 0);
        oB[mt] = __builtin_amdgcn_mfma_f32_16x16x32_bf16(vf1, pfB[1], oB[mt], 0, 0, 0);
      }
    }
  }

  // epilogue: reduce row-sums across the 4 quad groups, write O (bf16)
  // lane holds O^T[d=mt*16+quad*4+r][q=l15]
#pragma unroll
  for (int half = 0; half < 2; ++half) {
    float lp = half ? lB : lA;
    lp += __shfl_xor(lp, 16, 64);
    lp += __shfl_xor(lp, 32, 64);
    float inv = 1.0f / lp;
    const int qt = half ? qtB : qtA;
    const f32x4* o = half ? oB : oA;
    size_t rowbase = ((size_t)(bb * 2048 + qt * 64 + w * 16 + l15)) * 1024 + hh * 64;
#pragma unroll
    for (int mt = 0; mt < 4; ++mt) {
      u16x4 v;
#pragma unroll
      for (int r = 0; r < 4; ++r) v[r] = f2bf(o[mt][r] * inv);
      *(u16x4*)(Ao + rowbase + mt * 16 + quad * 4) = v;
    }
  }
}

extern "C" void kernel_launch(void* const* d_in, const int* in_sizes, int n_in,
                              void* d_out, int out_size, void* d_ws, size_t ws_size,
                              hipStream_t stream)
{
  (void)in_sizes; (void)n_in; (void)out_size; (void)ws_size;

  const float* xq = (const float*)d_in[0];
  const float* xk = (const float*)d_in[1];
  const float* xv = (const float*)d_in[2];
  // d_in[3] = mask (int32 tril) — causality applied analytically
  const float* Wq = (const float*)d_in[4];
  const float* bq = (const float*)d_in[5];
  const float* Wk = (const float*)d_in[6];
  const float* bk = (const float*)d_in[7];
  const float* Wv = (const float*)d_in[8];
  const float* bv = (const float*)d_in[9];
  const float* Wo = (const float*)d_in[10];
  const float* bo = (const float*)d_in[11];

  const size_t NX = (size_t)4194304;   // B*L*E
  const size_t NW = (size_t)1048576;   // E*E
  unsigned short* Qws  = (unsigned short*)d_ws;
  unsigned short* Kws  = Qws + NX;
  unsigned short* Vtws = Kws + NX;
  unsigned short* Aws  = Vtws + NX;
  unsigned short* Wqbf = Aws + NX;
  unsigned short* Wkbf = Wqbf + NW;
  unsigned short* Wvbf = Wkbf + NW;
  unsigned short* Wobf = Wvbf + NW;    // total 40 MB of d_ws

  dim3 gc(512, 1, 4);
  cvt_kernel<<<gc, 256, 0, stream>>>(Wq, Wk, Wv, Wo, Wqbf, Wkbf, Wvbf, Wobf);
  dim3 gp(32, 8, 3);
  proj_kernel<<<gp, 256, 0, stream>>>(xq, xk, xv, Wqbf, bq, Wkbf, bk,
                                      Wvbf, bv, Qws, Kws, Vtws);
  dim3 gf(16, 32, 1);
  flash_kernel<<<gf, 256, 0, stream>>>(Qws, Kws, Vtws, Aws);
  dim3 go(64, 8, 1);
  oproj_kernel<<<go, 256, 0, stream>>>(Aws, Wobf, bo, (float*)d_out);
}

// Round 7
// 234.029 us; speedup vs baseline: 1.1499x; 1.1499x over previous
//
#include <hip/hip_runtime.h>
#include <stdint.h>
#include <stddef.h>

// MultiHeadAttention: B=2, L=2048, E=1024, H=16, Dh=64. Global dtype f32.
// Internals bf16 MFMA. Pipeline (R7 = R5 revert + proj BN=64 for residency):
//   cvt    : f32 -> bf16 copies of x_q,x_k,x_v,Wq,Wk,Wv,Wo
//   proj   : 128x64 tiles (grid 1536 = 6 blocks/CU; was grid-limited at 3),
//            Q prescaled by 0.125*log2e; K -> [B,H,L,Dh]; V -> [B,H,Dh,L]
//   flash  : causal, no-max softmax, transposed S^T/O^T, paired q-tiles (R5)
//   oproj  : attn @ Wo^T + bo -> d_out f32 (64x128 tiles, R5)

#define AS1 __attribute__((address_space(1)))
#define AS3 __attribute__((address_space(3)))

typedef __attribute__((ext_vector_type(8))) __bf16 bf16x8;
typedef __attribute__((ext_vector_type(8))) unsigned short u16x8;
typedef __attribute__((ext_vector_type(4))) unsigned short u16x4;
typedef __attribute__((ext_vector_type(4))) float f32x4;
typedef __attribute__((ext_vector_type(2))) unsigned int u32x2;

// 0.125 * log2(e): folds 1/sqrt(Dh) AND exp->exp2 conversion into Q
#define QSCALE 0.18033688011112042f

static __device__ __forceinline__ unsigned short f2bf(float f) {
  unsigned int u = __builtin_bit_cast(unsigned int, f);
  u += 0x7fffu + ((u >> 16) & 1u);   // RNE
  return (unsigned short)(u >> 16);
}
// pack two f32 -> bf16 pair by truncation (1 v_perm); bias cancels in p/sum(p)
static __device__ __forceinline__ unsigned int pkbf(float lo, float hi) {
  return __builtin_amdgcn_perm(__builtin_bit_cast(unsigned int, hi),
                               __builtin_bit_cast(unsigned int, lo), 0x07060302u);
}
static __device__ __forceinline__ void g2l16(const unsigned short* g, unsigned short* l) {
  __builtin_amdgcn_global_load_lds((AS1 void*)g, (AS3 void*)l, 16, 0, 0);
}
static __device__ __forceinline__ float fexp2(float x) {
  return __builtin_amdgcn_exp2f(x);
}

// ---------------------------------------------------------------------------
// f32 -> bf16 bulk convert (x_q,x_k,x_v + 4 weights)
// ---------------------------------------------------------------------------
__global__ __launch_bounds__(256) void cvt_kernel(
    const float* __restrict__ s0, const float* __restrict__ s1,
    const float* __restrict__ s2, const float* __restrict__ s3,
    const float* __restrict__ s4, const float* __restrict__ s5,
    const float* __restrict__ s6,
    unsigned short* __restrict__ d0, unsigned short* __restrict__ d1,
    unsigned short* __restrict__ d2, unsigned short* __restrict__ d3,
    unsigned short* __restrict__ d4, unsigned short* __restrict__ d5,
    unsigned short* __restrict__ d6)
{
  const int z = blockIdx.z;
  const float* s; unsigned short* d; int n;
  switch (z) {
    case 0: s = s0; d = d0; n = 4194304; break;
    case 1: s = s1; d = d1; n = 4194304; break;
    case 2: s = s2; d = d2; n = 4194304; break;
    case 3: s = s3; d = d3; n = 1048576; break;
    case 4: s = s4; d = d4; n = 1048576; break;
    case 5: s = s5; d = d5; n = 1048576; break;
    default: s = s6; d = d6; n = 1048576; break;
  }
  int i = (blockIdx.x * 256 + threadIdx.x) * 8;
  if (i >= n) return;
  f32x4 a = *(const f32x4*)(s + i);
  f32x4 b = *(const f32x4*)(s + i + 4);
  u16x8 r;
  r[0] = f2bf(a[0]); r[1] = f2bf(a[1]); r[2] = f2bf(a[2]); r[3] = f2bf(a[3]);
  r[4] = f2bf(b[0]); r[5] = f2bf(b[1]); r[6] = f2bf(b[2]); r[7] = f2bf(b[3]);
  *(u16x8*)(d + i) = r;
}

// ---------------------------------------------------------------------------
// GEMM: out[m,n] = (sum_k A[m,k]*Bw[n,k] + bias[n]) * oscale
// BM x BN tile, BK=32, double-buffered LDS, ONE barrier per K-iter.
// 4 waves in 2x2 over (BM/2)x(BN/2) each. LDS rows 64B, chunk slot sl holds
// global chunk sl^((row>>1)&3) -> all reads 2-way-per-phase (measured 0).
// mode 0: outf f32 rm | mode 1: outb [B,H,L,Dh] bf16 | mode 2: [B,H,Dh,L]
// ---------------------------------------------------------------------------
template<int BM, int BN>
static __device__ __forceinline__ void gemm_bt(
    const unsigned short* __restrict__ A,
    const unsigned short* __restrict__ Bw,
    const float* __restrict__ bias,
    unsigned short* __restrict__ outb,
    float* __restrict__ outf,
    int K, int N, int mode, float oscale)
{
  constexpr int MT = BM / 32;
  constexpr int NT = BN / 32;
  __shared__ __align__(16) unsigned short As[2][BM * 32];
  __shared__ __align__(16) unsigned short Bs[2][BN * 32];

  const int t    = threadIdx.x;
  const int lane = t & 63;
  const int w    = t >> 6;
  const int quad = lane >> 4;
  const int l15  = lane & 15;
  const int wm   = (w >> 1) * (BM / 2);
  const int wn   = (w & 1) * (BN / 2);
  const int m0   = blockIdx.x * BM;
  const int n0   = blockIdx.y * BN;

  f32x4 acc[MT][NT];
  const f32x4 zero = {0.f, 0.f, 0.f, 0.f};
#pragma unroll
  for (int mt = 0; mt < MT; ++mt)
#pragma unroll
    for (int nt = 0; nt < NT; ++nt) acc[mt][nt] = zero;

  auto stage = [&](int buf, int k0) {
#pragma unroll
    for (int i = 0; i < BM / 64; ++i) {
      int c = t + i * 256;
      int row = c >> 2, sl = c & 3;
      int g = sl ^ ((row >> 1) & 3);
      g2l16(A + (size_t)(m0 + row) * K + (k0 + g * 8), &As[buf][c * 8]);
    }
#pragma unroll
    for (int i = 0; i < BN / 64; ++i) {
      int c = t + i * 256;
      int row = c >> 2, sl = c & 3;
      int g = sl ^ ((row >> 1) & 3);
      g2l16(Bw + (size_t)(n0 + row) * K + (k0 + g * 8), &Bs[buf][c * 8]);
    }
  };

  stage(0, 0);
  const int nk = K >> 5;
  for (int kt = 0; kt < nk; ++kt) {
    __syncthreads();
    if (kt + 1 < nk) stage((kt + 1) & 1, (kt + 1) * 32);
    const int b = kt & 1;

    bf16x8 af[MT], bfr[NT];
#pragma unroll
    for (int mt = 0; mt < MT; ++mt) {
      int r = wm + mt * 16 + l15;
      af[mt] = *(const bf16x8*)(&As[b][r * 32 + ((quad ^ ((r >> 1) & 3)) * 8)]);
    }
#pragma unroll
    for (int nt = 0; nt < NT; ++nt) {
      int r = wn + nt * 16 + l15;
      bfr[nt] = *(const bf16x8*)(&Bs[b][r * 32 + ((quad ^ ((r >> 1) & 3)) * 8)]);
    }
#pragma unroll
    for (int mt = 0; mt < MT; ++mt)
#pragma unroll
      for (int nt = 0; nt < NT; ++nt)
        acc[mt][nt] = __builtin_amdgcn_mfma_f32_16x16x32_bf16(af[mt], bfr[nt], acc[mt][nt], 0, 0, 0);
  }

#pragma unroll
  for (int nt = 0; nt < NT; ++nt) {
    int n = n0 + wn + nt * 16 + l15;
    float bv = bias[n];
#pragma unroll
    for (int mt = 0; mt < MT; ++mt) {
#pragma unroll
      for (int r = 0; r < 4; ++r) {
        int m = m0 + wm + mt * 16 + quad * 4 + r;
        float val = (acc[mt][nt][r] + bv) * oscale;
        if (mode == 0) {
          outf[(size_t)m * N + n] = val;
        } else {
          int b2 = m >> 11, l = m & 2047, h = n >> 6, d = n & 63;
          size_t idx;
          if (mode == 1) idx = ((size_t)(b2 * 16 + h) * 2048 + l) * 64 + d;
          else           idx = ((size_t)(b2 * 16 + h) * 64 + d) * 2048 + l;
          outb[idx] = f2bf(val);
        }
      }
    }
  }
}

// 128x64 tiles: grid (32,16,3) = 1536 blocks = 6/CU; LDS 24KB; 5 resident.
__global__ __launch_bounds__(256, 5) void proj_kernel(
    const unsigned short* __restrict__ xq, const unsigned short* __restrict__ xk,
    const unsigned short* __restrict__ xv,
    const unsigned short* __restrict__ Wq, const float* __restrict__ bq,
    const unsigned short* __restrict__ Wk, const float* __restrict__ bk,
    const unsigned short* __restrict__ Wv, const float* __restrict__ bv,
    unsigned short* __restrict__ Qws, unsigned short* __restrict__ Kws,
    unsigned short* __restrict__ Vtws)
{
  int z = blockIdx.z;
  const unsigned short* A = (z == 0) ? xq : (z == 1) ? xk : xv;
  const unsigned short* W = (z == 0) ? Wq : (z == 1) ? Wk : Wv;
  const float* bias       = (z == 0) ? bq : (z == 1) ? bk : bv;
  unsigned short* out     = (z == 0) ? Qws : (z == 1) ? Kws : Vtws;
  float oscale            = (z == 0) ? QSCALE : 1.0f;
  gemm_bt<128, 64>(A, W, bias, out, nullptr, 1024, 1024, (z == 2) ? 2 : 1, oscale);
}

__global__ __launch_bounds__(256, 4) void oproj_kernel(
    const unsigned short* __restrict__ Ain, const unsigned short* __restrict__ Wo,
    const float* __restrict__ bo, float* __restrict__ out)
{
  gemm_bt<64, 128>(Ain, Wo, bo, nullptr, out, 1024, 1024, 0, 1.0f);
}

// ---------------------------------------------------------------------------
// Causal flash attention (exact R5 version). Q,K: [B*H,2048,64] bf16
// (Q prescaled); Vt: [B*H,64,2048]. Block (pi,bh): q-tiles qtA=31-pi, qtB=pi
// share one kv sweep. S^T = K*Q^T; P [q][kv] b64 writes; O^T = Vt*P^T.
// Row-sum per-lane, reduced at epilogue. 1 barrier/iter, K/V double-buffered.
// ---------------------------------------------------------------------------
__global__ __launch_bounds__(256, 2) void flash_kernel(
    const unsigned short* __restrict__ Q,
    const unsigned short* __restrict__ Km,
    const unsigned short* __restrict__ Vt,
    unsigned short* __restrict__ Ao)
{
  __shared__ __align__(16) unsigned short Ks[2][64 * 64];
  __shared__ __align__(16) unsigned short Vs[2][64 * 64];
  __shared__ __align__(16) unsigned short PsA[4][16 * 64];
  __shared__ __align__(16) unsigned short PsB[4][16 * 64];

  const int t    = threadIdx.x;
  const int lane = t & 63;
  const int w    = t >> 6;
  const int quad = lane >> 4;
  const int l15  = lane & 15;
  const int pi   = blockIdx.x;      // 0..15
  const int bh   = blockIdx.y;
  const int qtA  = 31 - pi;
  const int qtB  = pi;              // qtB < qtA always

  const unsigned short* Qb = Q  + (size_t)bh * 2048 * 64;
  const unsigned short* Kb = Km + (size_t)bh * 2048 * 64;
  const unsigned short* Vb = Vt + (size_t)bh * 64 * 2048;
  const int bb = bh >> 4, hh = bh & 15;

  const f32x4 zero = {0.f, 0.f, 0.f, 0.f};

  // Q fragments, B-operand layout (n=q=l15, k=d=quad*8+j), 2 k-steps
  bf16x8 qfA[2], qfB[2];
#pragma unroll
  for (int s = 0; s < 2; ++s) {
    qfA[s] = *(const bf16x8*)(Qb + (size_t)(qtA * 64 + w * 16 + l15) * 64 + s * 32 + quad * 8);
    qfB[s] = *(const bf16x8*)(Qb + (size_t)(qtB * 64 + w * 16 + l15) * 64 + s * 32 + quad * 8);
  }

  f32x4 oA[4], oB[4];
#pragma unroll
  for (int mt = 0; mt < 4; ++mt) { oA[mt] = zero; oB[mt] = zero; }
  float lA = 0.f, lB = 0.f;

  auto stage = [&](int buf, int kv0) {
#pragma unroll
    for (int i = 0; i < 2; ++i) {
      int c = t + i * 256;
      int row = c >> 3, sl = c & 7;
      int g = sl ^ (row & 7);
      g2l16(Kb + (size_t)(kv0 + row) * 64 + g * 8, &Ks[buf][c * 8]);
      g2l16(Vb + (size_t)row * 2048 + kv0 + g * 8, &Vs[buf][c * 8]);
    }
  };

  stage(0, 0);

  // P-store address (wave-private): row q=l15; b64 chunk c=mt*4+quad at
  // elem off ((mt*2+(quad>>1))^(l15&7))*8 + (quad&1)*4  (bank-optimal)
  const int pwr = l15 * 64 + (quad & 1) * 4;
  const int pu0 = quad >> 1;
  const int ph  = l15 & 7;

#pragma unroll 1
  for (int it = 0; it <= qtA; ++it) {
    __syncthreads();
    const int cur = it & 1;
    if (it < qtA) stage(cur ^ 1, (it + 1) * 64);
    const bool doB = (it <= qtB);

    // K fragments, A-operand layout (m=kv=mt*16+l15, k=d): shared by A/B
    bf16x8 kf[4][2];
#pragma unroll
    for (int mt = 0; mt < 4; ++mt) {
      int kv = mt * 16 + l15;
#pragma unroll
      for (int s = 0; s < 2; ++s)
        kf[mt][s] = *(const bf16x8*)(&Ks[cur][kv * 64 + (((s * 4 + quad) ^ (kv & 7)) * 8)]);
    }

    // S^T = K Q^T : D[row=kv_local=mt*16+quad*4+r][col=q=l15]
    f32x4 sA[4], sB[4];
#pragma unroll
    for (int mt = 0; mt < 4; ++mt) {
      f32x4 z = zero;
      z = __builtin_amdgcn_mfma_f32_16x16x32_bf16(kf[mt][0], qfA[0], z, 0, 0, 0);
      z = __builtin_amdgcn_mfma_f32_16x16x32_bf16(kf[mt][1], qfA[1], z, 0, 0, 0);
      sA[mt] = z;
    }
    if (doB) {
#pragma unroll
      for (int mt = 0; mt < 4; ++mt) {
        f32x4 z = zero;
        z = __builtin_amdgcn_mfma_f32_16x16x32_bf16(kf[mt][0], qfB[0], z, 0, 0, 0);
        z = __builtin_amdgcn_mfma_f32_16x16x32_bf16(kf[mt][1], qfB[1], z, 0, 0, 0);
        sB[mt] = z;
      }
    }

    // causal mask on diagonal tiles: kv_local > q_local
    const int qloc = w * 16 + l15;
    if (it == qtA) {
#pragma unroll
      for (int mt = 0; mt < 4; ++mt)
#pragma unroll
        for (int r = 0; r < 4; ++r)
          if (mt * 16 + quad * 4 + r > qloc) sA[mt][r] = -30000.f;
    }
    if (it == qtB) {
#pragma unroll
      for (int mt = 0; mt < 4; ++mt)
#pragma unroll
        for (int r = 0; r < 4; ++r)
          if (mt * 16 + quad * 4 + r > qloc) sB[mt][r] = -30000.f;
    }

    // exp2 (no max subtraction — scores bounded), per-lane partial row-sum,
    // pack 4 bf16 -> one ds_write_b64 per mt
#pragma unroll
    for (int mt = 0; mt < 4; ++mt) {
      float p0 = fexp2(sA[mt][0]), p1 = fexp2(sA[mt][1]);
      float p2 = fexp2(sA[mt][2]), p3 = fexp2(sA[mt][3]);
      lA += (p0 + p1) + (p2 + p3);
      u32x2 pk = {pkbf(p0, p1), pkbf(p2, p3)};
      *(u32x2*)(&PsA[w][pwr + (((mt * 2 + pu0) ^ ph) * 8)]) = pk;
    }
    if (doB) {
#pragma unroll
      for (int mt = 0; mt < 4; ++mt) {
        float p0 = fexp2(sB[mt][0]), p1 = fexp2(sB[mt][1]);
        float p2 = fexp2(sB[mt][2]), p3 = fexp2(sB[mt][3]);
        lB += (p0 + p1) + (p2 + p3);
        u32x2 pk = {pkbf(p0, p1), pkbf(p2, p3)};
        *(u32x2*)(&PsB[w][pwr + (((mt * 2 + pu0) ^ ph) * 8)]) = pk;
      }
    }

    // O^T += Vt P^T : A = Vs (m=d=mt*16+l15, k=kv), B = P (n=q=l15, k=kv)
    bf16x8 pfA[2], pfB[2];
#pragma unroll
    for (int s = 0; s < 2; ++s)
      pfA[s] = *(const bf16x8*)(&PsA[w][l15 * 64 + (((s * 4 + quad) ^ ph) * 8)]);
    if (doB) {
#pragma unroll
      for (int s = 0; s < 2; ++s)
        pfB[s] = *(const bf16x8*)(&PsB[w][l15 * 64 + (((s * 4 + quad) ^ ph) * 8)]);
    }
#pragma unroll
    for (int mt = 0; mt < 4; ++mt) {
      int dd = mt * 16 + l15;
      bf16x8 vf0 = *(const bf16x8*)(&Vs[cur][dd * 64 + (((quad)     ^ (dd & 7)) * 8)]);
      bf16x8 vf1 = *(const bf16x8*)(&Vs[cur][dd * 64 + (((4 + quad) ^ (dd & 7)) * 8)]);
      oA[mt] = __builtin_amdgcn_mfma_f32_16x16x32_bf16(vf0, pfA[0], oA[mt], 0, 0, 0);
      oA[mt] = __builtin_amdgcn_mfma_f32_16x16x32_bf16(vf1, pfA[1], oA[mt], 0, 0, 0);
      if (doB) {
        oB[mt] = __builtin_amdgcn_mfma_f32_16x16x32_bf16(vf0, pfB[0], oB[mt], 0, 0, 0);
        oB[mt] = __builtin_amdgcn_mfma_f32_16x16x32_bf16(vf1, pfB[1], oB[mt], 0, 0, 0);
      }
    }
  }

  // epilogue: reduce row-sums across the 4 quad groups, write O (bf16)
  // lane holds O^T[d=mt*16+quad*4+r][q=l15]
#pragma unroll
  for (int half = 0; half < 2; ++half) {
    float lp = half ? lB : lA;
    lp += __shfl_xor(lp, 16, 64);
    lp += __shfl_xor(lp, 32, 64);
    float inv = 1.0f / lp;
    const int qt = half ? qtB : qtA;
    const f32x4* o = half ? oB : oA;
    size_t rowbase = ((size_t)(bb * 2048 + qt * 64 + w * 16 + l15)) * 1024 + hh * 64;
#pragma unroll
    for (int mt = 0; mt < 4; ++mt) {
      u16x4 v;
#pragma unroll
      for (int r = 0; r < 4; ++r) v[r] = f2bf(o[mt][r] * inv);
      *(u16x4*)(Ao + rowbase + mt * 16 + quad * 4) = v;
    }
  }
}

extern "C" void kernel_launch(void* const* d_in, const int* in_sizes, int n_in,
                              void* d_out, int out_size, void* d_ws, size_t ws_size,
                              hipStream_t stream)
{
  (void)in_sizes; (void)n_in; (void)out_size; (void)ws_size;

  const float* xq = (const float*)d_in[0];
  const float* xk = (const float*)d_in[1];
  const float* xv = (const float*)d_in[2];
  // d_in[3] = mask (int32 tril) — causality applied analytically
  const float* Wq = (const float*)d_in[4];
  const float* bq = (const float*)d_in[5];
  const float* Wk = (const float*)d_in[6];
  const float* bk = (const float*)d_in[7];
  const float* Wv = (const float*)d_in[8];
  const float* bv = (const float*)d_in[9];
  const float* Wo = (const float*)d_in[10];
  const float* bo = (const float*)d_in[11];

  const size_t NX = (size_t)4194304;   // B*L*E
  const size_t NW = (size_t)1048576;   // E*E
  unsigned short* Qws  = (unsigned short*)d_ws;
  unsigned short* Kws  = Qws + NX;
  unsigned short* Vtws = Kws + NX;
  unsigned short* xqbf = Vtws + NX;    // aliased as Aws after proj completes
  unsigned short* xkbf = xqbf + NX;
  unsigned short* xvbf = xkbf + NX;
  unsigned short* Wqbf = xvbf + NX;
  unsigned short* Wkbf = Wqbf + NW;
  unsigned short* Wvbf = Wkbf + NW;
  unsigned short* Wobf = Wvbf + NW;
  unsigned short* Aws  = xqbf;         // flash output reuses xq bf16 buffer

  dim3 gc(2048, 1, 7);
  cvt_kernel<<<gc, 256, 0, stream>>>(xq, xk, xv, Wq, Wk, Wv, Wo,
                                     xqbf, xkbf, xvbf, Wqbf, Wkbf, Wvbf, Wobf);
  dim3 gp(32, 16, 3);
  proj_kernel<<<gp, 256, 0, stream>>>(xqbf, xkbf, xvbf, Wqbf, bq, Wkbf, bk,
                                      Wvbf, bv, Qws, Kws, Vtws);
  dim3 gf(16, 32, 1);
  flash_kernel<<<gf, 256, 0, stream>>>(Qws, Kws, Vtws, Aws);
  dim3 go(64, 8, 1);
  oproj_kernel<<<go, 256, 0, stream>>>(Aws, Wobf, bo, (float*)d_out);
}